// Round 1
// baseline (328.049 us; speedup 1.0000x reference)
//
#include <hip/hip_runtime.h>

// DIN attention layer: B=2048, L=200, E=128, H=64.  R3: async HBM->LDS staging.
// Theory: main loop was memory-LATENCY-bound (per-wave in-flight window ~8
// outstanding 16B/lane register loads). Replace with global_load_lds dwordx4
// (1 KiB in flight per instruction, zero VGPR cost) into wave-private
// double-buffered f32 staging, counted vmcnt(8) waits (T3/T4, barrier-free).
// Keys kept resident in bf16 A-frags for the weighted sum; LDS keys copy and
// its swizzled writes removed entirely. Staging reads made conflict-free by
// XOR-swizzling the 16B blocks via the pre-swizzled GLOBAL source (dest of
// global_load_lds must stay linear).

#define NB 2048
#define LE 128   // E
#define LH 64    // H
#define LL 200   // L

typedef short bf16x8 __attribute__((ext_vector_type(8)));
typedef float f32x4 __attribute__((ext_vector_type(4)));

__device__ __forceinline__ short f2bf(float f) {  // RNE float->bf16
  unsigned u = __float_as_uint(f);
  u += 0x7fffu + ((u >> 16) & 1u);
  return (short)(u >> 16);
}

__device__ __forceinline__ void gll16(const void* g, void* l) {
  __builtin_amdgcn_global_load_lds(
      (const __attribute__((address_space(1))) void*)g,
      (__attribute__((address_space(3))) void*)l, 16, 0, 0);
}

struct __align__(16) SM {
  union {
    float stag[4][2][16 * 128];  // 65536 B: per-wave dbuf f32 key tiles
    short scratch[64 * 136];     // prologue Wk overlay (dead before staging)
  } u;
  short h1[4][16 * 72];  // 9216 B; overlays: bias partials (prologue), redf (wsum)
  float scores[208];
  float q[128];
  float bias1[64];
  float b2s[64];
  float w3s[64];
  float red[16];
};  // total 76928 B -> 2 WG/CU

// ---- K0: b-independent weight prep into workspace (unchanged) -------------
__global__ void k0_prep(const float* __restrict__ W1, const float* __restrict__ W2,
                        float* __restrict__ BD, float* __restrict__ Cq,
                        float* __restrict__ AD, short* __restrict__ W2T) {
  int idx = blockIdx.x * 256 + threadIdx.x;  // 32 blocks * 256 = 8192
  if (idx < 8192) {
    int h = idx >> 7, e = idx & 127;
    BD[idx] = W1[(128 + e) * LH + h] - W1[(384 + e) * LH + h];
    Cq[idx] = W1[(256 + e) * LH + h];
    int e2 = idx >> 6, h2 = idx & 63;
    AD[idx] = W1[e2 * LH + h2] + W1[(384 + e2) * LH + h2];
    if (idx < 4096) {
      int c = idx >> 6, k = idx & 63;
      W2T[idx] = f2bf(W2[k * LH + c]);
    }
  }
}

__global__ void __launch_bounds__(256, 2)
din_attn(const float* __restrict__ query, const float* __restrict__ keysg,
         const int* __restrict__ mask, const float* __restrict__ b1,
         const float* __restrict__ b2, const float* __restrict__ W3,
         const float* __restrict__ no_hist,
         const float* __restrict__ BD, const float* __restrict__ Cq,
         const float* __restrict__ AD, const short* __restrict__ W2T,
         float* __restrict__ out)
{
  __shared__ SM sm;
  const int b    = blockIdx.x;
  const int t    = threadIdx.x;
  const int lane = t & 63;
  const int wv   = t >> 6;
  const int col  = lane & 15;   // MFMA m/n index
  const int quad = lane >> 4;   // MFMA k-group
  const int l31  = lane & 31;
  const int lh   = lane >> 5;

  // ---- prologue: tiny loads
  int my_mask = 0;
  if (t < LL) my_mask = mask[b * LL + t];
  if (t < LE) sm.q[t] = query[b * LE + t];
  if (t < LH) { sm.b2s[t] = b2[t]; sm.w3s[t] = W3[t]; }
  __syncthreads();  // q visible

  // layer-2 B-frags straight from W2T (global, frag-contiguous)
  bf16x8 fB2[4][2];
  #pragma unroll
  for (int n = 0; n < 4; ++n)
    #pragma unroll
    for (int k2 = 0; k2 < 2; ++k2)
      fB2[n][k2] = *(const bf16x8*)&W2T[(n * 16 + col) * 64 + k2 * 32 + quad * 8];

  // Wk[h][e] = BD + q_e*Cq -> bf16 scratch (overlaid on staging region)
  short* scratch = &sm.u.scratch[0];  // 64 rows x 136 shorts
  #pragma unroll
  for (int i = 0; i < 4; ++i) {
    int idx = (t + 256 * i) * 8;
    int h = idx >> 7, e0 = idx & 127;
    float4 bd0 = *(const float4*)&BD[idx];
    float4 bd1 = *(const float4*)&BD[idx + 4];
    float4 c0  = *(const float4*)&Cq[idx];
    float4 c1  = *(const float4*)&Cq[idx + 4];
    bf16x8 w;
    w[0] = f2bf(bd0.x + sm.q[e0 + 0] * c0.x);
    w[1] = f2bf(bd0.y + sm.q[e0 + 1] * c0.y);
    w[2] = f2bf(bd0.z + sm.q[e0 + 2] * c0.z);
    w[3] = f2bf(bd0.w + sm.q[e0 + 3] * c0.w);
    w[4] = f2bf(bd1.x + sm.q[e0 + 4] * c1.x);
    w[5] = f2bf(bd1.y + sm.q[e0 + 5] * c1.y);
    w[6] = f2bf(bd1.z + sm.q[e0 + 6] * c1.z);
    w[7] = f2bf(bd1.w + sm.q[e0 + 7] * c1.w);
    *(bf16x8*)&scratch[h * 136 + e0] = w;
  }
  // bias1 partials: wave wv sums e-quarter wv
  {
    int h = lane;
    float acc = 0.f;
    #pragma unroll 8
    for (int e = wv * 32; e < wv * 32 + 32; ++e)
      acc = fmaf(sm.q[e], AD[e * LH + h], acc);
    float* biasp = (float*)&sm.h1[0][0];  // 4 x 64 floats
    biasp[wv * 64 + h] = acc;
  }
  __syncthreads();  // barrier A: scratch + partials visible

  bf16x8 fB1[4][4];
  #pragma unroll
  for (int n = 0; n < 4; ++n)
    #pragma unroll
    for (int kt = 0; kt < 4; ++kt)
      fB1[n][kt] = *(const bf16x8*)&scratch[(n * 16 + col) * 136 + kt * 32 + quad * 8];

  if (t < LH) {
    const float* biasp = (const float*)&sm.h1[0][0];
    sm.bias1[t] = b1[t] + biasp[t] + biasp[64 + t] + biasp[128 + t] + biasp[192 + t];
  }
  __syncthreads();  // barrier B: frags read (scratch dead -> staging may begin)

  // ---- barrier-free async main loop: wave wv owns tiles {wv, wv+4, wv+8} (+12 for wv==0)
  const float* kb = keysg + (size_t)b * LL * LE;
  short* h1w = &sm.h1[wv][0];
  const int mts[4] = {wv, wv + 4, wv + 8, 12};
  const int nt = (wv == 0) ? 4 : 3;
  float* stg0 = &sm.u.stag[wv][0][0];
  float* stg1 = &sm.u.stag[wv][1][0];

  // 8 x global_load_lds dwordx4 per 16x128 f32 tile. Instruction i covers
  // staging rows 2i,2i+1 (one aligned 1 KiB global span). 16B blocks are
  // XOR-swizzled by (row&7) via the per-lane GLOBAL address (dest linear).
  auto issue_tile = [&](float* dst, int mt) {
    #pragma unroll
    for (int i = 0; i < 8; ++i) {
      int rl  = 2 * i + lh;              // staging-local row 0..15
      int row = mt * 16 + rl;
      row = row < LL ? row : LL - 1;     // clamp only matters for mt==12
      const float* src = kb + row * LE + ((l31 ^ (rl & 7)) << 2);
      gll16(src, dst + i * 256);
    }
  };

  // staging -> bf16 A-frags; reads are 2-way (free) thanks to the swizzle
  auto load_frags = [&](const float* sb, bf16x8 (&a)[4]) {
    #pragma unroll
    for (int kt = 0; kt < 4; ++kt) {
      const int b0 = kt * 8 + quad * 2;  // 16B block index 0..31
      float4 v0 = *(const float4*)&sb[col * 128 + ((b0 ^ (col & 7)) << 2)];
      float4 v1 = *(const float4*)&sb[col * 128 + (((b0 + 1) ^ (col & 7)) << 2)];
      bf16x8 av;
      av[0] = f2bf(v0.x); av[1] = f2bf(v0.y); av[2] = f2bf(v0.z); av[3] = f2bf(v0.w);
      av[4] = f2bf(v1.x); av[5] = f2bf(v1.y); av[6] = f2bf(v1.z); av[7] = f2bf(v1.w);
      a[kt] = av;
    }
  };

  auto compute_tile = [&](const bf16x8 (&a)[4], int mt) {
    #pragma unroll
    for (int n = 0; n < 4; ++n) {
      f32x4 acc = {0.f, 0.f, 0.f, 0.f};
      #pragma unroll
      for (int kt = 0; kt < 4; ++kt)
        acc = __builtin_amdgcn_mfma_f32_16x16x32_bf16(a[kt], fB1[n][kt], acc, 0, 0, 0);
      float bias = sm.bias1[n * 16 + col];
      #pragma unroll
      for (int j = 0; j < 4; ++j)  // C layout: row=quad*4+j, col
        h1w[(quad * 4 + j) * 72 + n * 16 + col] = f2bf(fmaxf(acc[j] + bias, 0.f));
    }
    bf16x8 a2[2];  // wave-local LDS round-trip (no __syncthreads needed)
    #pragma unroll
    for (int k2 = 0; k2 < 2; ++k2)
      a2[k2] = *(const bf16x8*)&h1w[col * 72 + k2 * 32 + quad * 8];
    float p[4] = {0.f, 0.f, 0.f, 0.f};
    #pragma unroll
    for (int n = 0; n < 4; ++n) {
      f32x4 c2 = {0.f, 0.f, 0.f, 0.f};
      c2 = __builtin_amdgcn_mfma_f32_16x16x32_bf16(a2[0], fB2[n][0], c2, 0, 0, 0);
      c2 = __builtin_amdgcn_mfma_f32_16x16x32_bf16(a2[1], fB2[n][1], c2, 0, 0, 0);
      float bb = sm.b2s[n * 16 + col];
      float w3 = sm.w3s[n * 16 + col];
      #pragma unroll
      for (int j = 0; j < 4; ++j)
        p[j] = fmaf(fmaxf(c2[j] + bb, 0.f), w3, p[j]);  // layer 3 fused; b3 dropped
    }
    #pragma unroll
    for (int j = 0; j < 4; ++j) {
      #pragma unroll
      for (int off = 1; off < 16; off <<= 1)
        p[j] += __shfl_xor(p[j], off);  // reduce over 16 cols
      if (col == 0) sm.scores[mt * 16 + quad * 4 + j] = p[j];
    }
  };

  issue_tile(stg0, mts[0]);   // 8 outstanding
  issue_tile(stg1, mts[1]);   // 16 outstanding

  bf16x8 ka[4][4];  // keys stay resident for the weighted sum (static idx only)
  #pragma unroll
  for (int i = 0; i < 4; ++i) {
    if (i < nt) {
      // counted wait: tile i complete, next tile's 8 loads stay in flight
      if (i < nt - 1) asm volatile("s_waitcnt vmcnt(8)" ::: "memory");
      else            asm volatile("s_waitcnt vmcnt(0)" ::: "memory");
      __builtin_amdgcn_sched_barrier(0);
      load_frags((i & 1) ? stg1 : stg0, ka[i]);
      asm volatile("s_waitcnt lgkmcnt(0)" ::: "memory");  // staging reads done
      __builtin_amdgcn_sched_barrier(0);
      if (i + 2 < nt) issue_tile((i & 1) ? stg1 : stg0, mts[i + 2]);
      __builtin_amdgcn_sched_barrier(0);  // pin prefetch issue before MFMAs
      compute_tile(ka[i], mts[i]);
    }
  }
  __syncthreads();  // scores complete

  // ---- masked softmax over L (fp32; matches ref incl. all-pad handling)
  float sc = (t < LL) ? sm.scores[t] : -3.0e38f;
  float vmax = (my_mask != 0) ? sc : -3.0e38f;
  #pragma unroll
  for (int off = 1; off < 64; off <<= 1) vmax = fmaxf(vmax, __shfl_xor(vmax, off));
  if (lane == 0) sm.red[wv] = vmax;
  __syncthreads();
  float M = fmaxf(fmaxf(sm.red[0], sm.red[1]), fmaxf(sm.red[2], sm.red[3]));
  float ex = (t < LL && my_mask != 0) ? __expf(sc - M) : 0.f;
  float vsum = ex;
  #pragma unroll
  for (int off = 1; off < 64; off <<= 1) vsum += __shfl_xor(vsum, off);
  if (lane == 0) sm.red[4 + wv] = vsum;
  __syncthreads();
  float Z = sm.red[4] + sm.red[5] + sm.red[6] + sm.red[7];
  bool allpad = !(Z > 0.f);
  float rz = allpad ? 0.f : (1.f / Z);
  if (t < 208) sm.scores[t] = (t < LL) ? ex * rz : 0.f;
  __syncthreads();

  // ---- weighted sum from register-resident keys:
  // lane holds keys[mts[i]*16+col][kt*32+quad*8 .. +7]; reduce over col.
  {
    float aw[4] = {0.f, 0.f, 0.f, 0.f};
    #pragma unroll
    for (int i = 0; i < 4; ++i)
      if (i < nt) aw[i] = sm.scores[mts[i] * 16 + col];  // rows>=200 -> 0

    float* redf = (float*)&sm.h1[0][0];  // 4 x 128 floats (h1 dead)
    #pragma unroll
    for (int kt = 0; kt < 4; ++kt) {
      float s[8] = {0.f, 0.f, 0.f, 0.f, 0.f, 0.f, 0.f, 0.f};
      #pragma unroll
      for (int i = 0; i < 4; ++i) {
        if (i < nt) {
          const int* kv = (const int*)&ka[i][kt];
          #pragma unroll
          for (int w = 0; w < 4; ++w) {
            unsigned u = (unsigned)kv[w];
            s[2 * w]     = fmaf(aw[i], __uint_as_float(u << 16), s[2 * w]);
            s[2 * w + 1] = fmaf(aw[i], __uint_as_float(u & 0xffff0000u), s[2 * w + 1]);
          }
        }
      }
      #pragma unroll
      for (int j = 0; j < 8; ++j) {
        #pragma unroll
        for (int off = 1; off < 16; off <<= 1)
          s[j] += __shfl_xor(s[j], off);  // reduce over the 16 cols (rows)
      }
      if (col == 0) {
        #pragma unroll
        for (int j = 0; j < 8; ++j)
          redf[wv * 128 + kt * 32 + quad * 8 + j] = s[j];
      }
    }
    __syncthreads();
    if (t < LE) {
      float s = redf[t] + redf[128 + t] + redf[256 + t] + redf[384 + t];
      if (allpad) s = no_hist[t];
      out[b * LE + t] = s;
    }
  }
}

extern "C" void kernel_launch(void* const* d_in, const int* in_sizes, int n_in,
                              void* d_out, int out_size, void* d_ws, size_t ws_size,
                              hipStream_t stream) {
  (void)in_sizes; (void)n_in; (void)ws_size; (void)out_size;
  const float* query   = (const float*)d_in[0];
  const float* keysg   = (const float*)d_in[1];
  const int*   mask    = (const int*)d_in[2];
  const float* W1      = (const float*)d_in[3];
  const float* b1      = (const float*)d_in[4];
  const float* W2      = (const float*)d_in[5];
  const float* b2      = (const float*)d_in[6];
  const float* W3      = (const float*)d_in[7];
  // d_in[8] = b3: unused (softmax shift-invariant)
  const float* no_hist = (const float*)d_in[9];

  float* BD  = (float*)d_ws;            // 8192 f32
  float* Cq  = BD + 8192;               // 8192 f32
  float* AD  = Cq + 8192;               // 8192 f32
  short* W2T = (short*)(AD + 8192);     // 4096 bf16   (total 106496 B)

  k0_prep<<<32, 256, 0, stream>>>(W1, W2, BD, Cq, AD, W2T);
  din_attn<<<NB, 256, 0, stream>>>(query, keysg, mask, b1, b2, W3, no_hist,
                                   BD, Cq, AD, W2T, (float*)d_out);
}